// Round 20
// baseline (230.152 us; speedup 1.0000x reference)
//
#include <hip/hip_runtime.h>
#include <hip/hip_bf16.h>
#include <stdint.h>

// ScaleGNN on MI355X (gfx950). fp32 in / fp32 out. edge_index int32/int64
// auto-detect (in scatter). Mask = JAX threefry2x32 key(42) bit-exact.
// R20: R19 + software-pipelined topk tile loop — prefetch next tile's
//      B-fragments (xnb loads, ~200cyc L2) before current tile's MFMA+scan.
//      +16 VGPR (<=64 keeps 4 blocks/CU). Everything else identical to R19.

#define N_NODES 4096
#define C_DIM   128
#define WPR     128        // bitmask words per row (4096/32)
#define HALF_P  8388608u   // N*N/2
#define TOPK    10
#define LSTR    13         // topk list stride; (16L+13c) mod 32 covers banks
#define JSPLIT  4          // topk j-split
#define KSPLIT  2          // fused K-split

typedef __attribute__((ext_vector_type(8))) short bf16x8;   // 8 bf16 = 4 VGPRs
typedef __attribute__((ext_vector_type(4))) float f32x4;    // MFMA C/D

__device__ __forceinline__ uint16_t f2bf(float f) {         // RNE fp32->bf16
    uint32_t u = __float_as_uint(f);
    return (uint16_t)((u + 0x7FFFu + ((u >> 16) & 1u)) >> 16);
}

__device__ __forceinline__ uint32_t rotl32(uint32_t v, int r) {
    return (v << r) | (v >> (32 - r));
}

__device__ __forceinline__ void threefry2x32(uint32_t k0, uint32_t k1,
                                             uint32_t x0, uint32_t x1,
                                             uint32_t& o0, uint32_t& o1) {
    uint32_t ks2 = k0 ^ k1 ^ 0x1BD11BDAu;
    x0 += k0; x1 += k1;
#define TF_ROUND(r) { x0 += x1; x1 = rotl32(x1, (r)); x1 ^= x0; }
    TF_ROUND(13) TF_ROUND(15) TF_ROUND(26) TF_ROUND(6)
    x0 += k1;  x1 += ks2 + 1u;
    TF_ROUND(17) TF_ROUND(29) TF_ROUND(16) TF_ROUND(24)
    x0 += ks2; x1 += k0 + 2u;
    TF_ROUND(13) TF_ROUND(15) TF_ROUND(26) TF_ROUND(6)
    x0 += k0;  x1 += k1 + 3u;
    TF_ROUND(17) TF_ROUND(29) TF_ROUND(16) TF_ROUND(24)
    x0 += k1;  x1 += ks2 + 4u;
    TF_ROUND(13) TF_ROUND(15) TF_ROUND(26) TF_ROUND(6)
    x0 += ks2; x1 += k0 + 5u;
#undef TF_ROUND
    o0 = x0; o1 = x1;
}

// ---- scatter edges (int64/int32 detected per block) -----------------------
__global__ void scatter_kernel(const int* __restrict__ ei, int E,
                               uint32_t* __restrict__ Abits) {
    __shared__ int cnt_oddnz;
    int t = threadIdx.x;
    if (t == 0) cnt_oddnz = 0;
    __syncthreads();
    if (((const uint32_t*)ei)[2 * t + 1] != 0u) atomicAdd(&cnt_oddnz, 1);
    __syncthreads();
    bool is64 = (cnt_oddnz <= 8);        // int64 => high words all zero
    int e = blockIdx.x * blockDim.x + t;
    if (e >= E) return;
    int src, dst;
    if (is64) { src = ei[2 * e]; dst = ei[2 * (E + e)]; }
    else      { src = ei[e];     dst = ei[E + e]; }
    src &= (N_NODES - 1);
    dst &= (N_NODES - 1);
    atomicOr(&Abits[src * WPR + (dst >> 5)], 1u << (dst & 31));
}

// ---- SpMM + norm: hop1 = A@x; xnb = bf16(x/(||x||+1e-8)) ------------------
__global__ void spmm_norm_kernel(const uint32_t* __restrict__ Abits,
                                 const float* __restrict__ xf,
                                 float* __restrict__ hop1,
                                 uint16_t* __restrict__ xnb) {
    int i = blockIdx.x;
    int c = threadIdx.x;                 // 128
    __shared__ uint32_t wbits[WPR];
    __shared__ float ws[2];
    wbits[c] = Abits[i * WPR + c];
    __syncthreads();
    float acc = 0.f;
    for (int w = 0; w < WPR; ++w) {
        uint32_t bits = wbits[w];
        while (bits) {
            int b = __ffs(bits) - 1;
            bits &= bits - 1;
            acc += xf[(w * 32 + b) * C_DIM + c];
        }
    }
    hop1[i * C_DIM + c] = acc;
    // norm of row i
    float v = xf[i * C_DIM + c];
    float sq = v * v;
    #pragma unroll
    for (int off = 32; off >= 1; off >>= 1) sq += __shfl_xor(sq, off);
    if ((c & 63) == 0) ws[c >> 6] = sq;
    __syncthreads();
    float tot = ws[0] + ws[1];
    xnb[i * C_DIM + c] = f2bf(v / (sqrtf(tot) + 1e-8f));
}

// ---- heterogeneous: blocks 0..1023 = topk; 1024..2047 = combo -------------
__launch_bounds__(512, 4)
__global__ void combo_topk_kernel(const uint32_t* __restrict__ Abits,
                                  const float* __restrict__ hop1,
                                  const float* __restrict__ xf,
                                  const float* __restrict__ alpha,
                                  uint16_t* __restrict__ aggTb,
                                  const uint16_t* __restrict__ xnb,
                                  uint32_t* __restrict__ Mbits,
                                  int* __restrict__ degInt,
                                  float* __restrict__ topv,
                                  int* __restrict__ topi) {
    __shared__ uint8_t smem[32 * 16 * LSTR * 6];   // 39936 B overlay
    int t = threadIdx.x;

    if (blockIdx.x < 1024) {
        // ================= topk (software-pipelined tiles) =================
        float*    sval = (float*)smem;                      // 26624 B
        uint16_t* sidx = (uint16_t*)(smem + 32 * 16 * LSTR * 4);
        int it   = blockIdx.x & 255;
        int part = blockIdx.x >> 8;      // 0..3
        int i0 = it * 16;
        int w = t >> 6;
        int lane = t & 63;
        int col = lane & 15;
        int quad = lane >> 4;

        bf16x8 bfi[4];
        #pragma unroll
        for (int s = 0; s < 4; ++s)
            bfi[s] = *(const bf16x8*)&xnb[(size_t)(i0 + col) * C_DIM + s * 32 + quad * 8];

        float tv[TOPK]; int ti[TOPK];
        #pragma unroll
        for (int k = 0; k < TOPK; ++k) { tv[k] = -1e30f; ti[k] = 0xFFFF; }

        int jt0 = part * 64 + w * 8;
        // prefetch tile 0's B-fragments
        bf16x8 ajn[4];
        {
            int j0 = jt0 * 16;
            #pragma unroll
            for (int s = 0; s < 4; ++s)
                ajn[s] = *(const bf16x8*)&xnb[(size_t)(j0 + col) * C_DIM + s * 32 + quad * 8];
        }
        for (int p = 0; p < 8; ++p) {
            int j0 = (jt0 + p) * 16;
            bf16x8 ajc[4];
            #pragma unroll
            for (int s = 0; s < 4; ++s) ajc[s] = ajn[s];
            if (p < 7) {                 // issue next tile's loads NOW
                int j1 = (jt0 + p + 1) * 16;
                #pragma unroll
                for (int s = 0; s < 4; ++s)
                    ajn[s] = *(const bf16x8*)&xnb[(size_t)(j1 + col) * C_DIM + s * 32 + quad * 8];
            }
            f32x4 acc = {0.f, 0.f, 0.f, 0.f};
            #pragma unroll
            for (int s = 0; s < 4; ++s)
                acc = __builtin_amdgcn_mfma_f32_16x16x32_bf16(ajc[s], bfi[s], acc, 0, 0, 0);
            float m4 = fmaxf(fmaxf(acc[0], acc[1]), fmaxf(acc[2], acc[3]));
            if (m4 > tv[TOPK-1]) {
                #pragma unroll
                for (int r = 0; r < 4; ++r) {
                    float d = acc[r];
                    if (d > tv[TOPK-1]) {    // strict > keeps earliest j
                        int j = j0 + quad * 4 + r;
                        tv[TOPK-1] = d; ti[TOPK-1] = j;
                        #pragma unroll
                        for (int q = TOPK - 2; q >= 0; --q) {
                            if (tv[q+1] > tv[q]) {
                                float fv = tv[q]; tv[q] = tv[q+1]; tv[q+1] = fv;
                                int iv = ti[q];  ti[q] = ti[q+1];  ti[q+1] = iv;
                            }
                        }
                    }
                }
            }
        }

        int base = ((w * 4 + quad) * 16 + col) * LSTR;
        #pragma unroll
        for (int k = 0; k < TOPK; ++k) {
            sval[base + k] = tv[k];
            sidx[base + k] = (uint16_t)ti[k];
        }

        int row = t & 15, L = t >> 4;
        for (int s = 16; s >= 1; s >>= 1) {
            __syncthreads();
            if (L < s) {
                int la = (L * 16 + row) * LSTR;
                int lb = ((L + s) * 16 + row) * LSTR;
                float ov[TOPK]; uint16_t oi[TOPK];
                int ia = 0, ib = 0;
                #pragma unroll
                for (int k = 0; k < TOPK; ++k) {
                    float va = sval[la + ia], vb = sval[lb + ib];
                    uint16_t xa = sidx[la + ia], xb = sidx[lb + ib];
                    bool takeA = (va > vb) || (va == vb && xa < xb);
                    if (takeA) { ov[k] = va; oi[k] = xa; ++ia; }
                    else       { ov[k] = vb; oi[k] = xb; ++ib; }
                }
                #pragma unroll
                for (int k = 0; k < TOPK; ++k) { sval[la + k] = ov[k]; sidx[la + k] = oi[k]; }
            }
        }
        __syncthreads();
        if (t < 16) {
            size_t gi = (size_t)(part * N_NODES + i0 + t) * TOPK;
            #pragma unroll
            for (int k = 0; k < TOPK; ++k) {
                topv[gi + k] = sval[t * LSTR + k];
                topi[gi + k] = (int)sidx[t * LSTR + k];
            }
        }
    } else {
        // ================= combo (4 rows per block) =================
        uint32_t* wb = (uint32_t*)smem;  // [4][128] = 2048 B
        int bid = blockIdx.x - 1024;
        int sg = t >> 7;                 // 0..3
        int c  = t & 127;
        int i  = bid * 4 + sg;
        wb[sg * 128 + c] = Abits[i * WPR + c];
        __syncthreads();
        float acc = 0.f;
        for (int w = 0; w < WPR; ++w) {
            uint32_t bits = wb[sg * 128 + w];
            while (bits) {
                int b = __ffs(bits) - 1;
                bits &= bits - 1;
                acc += hop1[(w * 32 + b) * C_DIM + c];
            }
        }
        float xv  = xf[i * C_DIM + c];
        float h1v = hop1[i * C_DIM + c];
        float a = alpha[0] * xv + alpha[1] * h1v + alpha[2] * acc;
        aggTb[(size_t)c * N_NODES + i] = f2bf(a);   // only consumer is fused

        // threefry mask: job u = i*128 + c (bit-exact original mapping)
        uint32_t u = (uint32_t)(i * 128 + c);
        uint32_t tid = u >> 1;
        uint32_t halfb = u & 1u;
        uint32_t base = tid * 32u + halfb * 16u;
        uint32_t w0 = 0u, w1 = 0u;
        for (int k = 0; k < 16; ++k) {
            uint32_t o0, o1;
            threefry2x32(0u, 42u, base + k, HALF_P + base + k, o0, o1);
            w0 |= (uint32_t)((o0 >> 31) ^ 1u) << k;
            w1 |= (uint32_t)((o1 >> 31) ^ 1u) << k;
        }
        uint32_t w0o = (uint32_t)__shfl_xor((int)w0, 1);
        uint32_t w1o = (uint32_t)__shfl_xor((int)w1, 1);
        int p0 = 0, p1 = 0;
        if (halfb == 0u) {
            uint32_t W0 = w0 | (w0o << 16);
            uint32_t W1 = w1 | (w1o << 16);
            Mbits[tid] = W0;
            Mbits[(HALF_P >> 5) + tid] = W1;
            p0 = __popc(W0); p1 = __popc(W1);
        }
        #pragma unroll
        for (int off = 32; off >= 1; off >>= 1) {
            p0 += __shfl_xor(p0, off);
            p1 += __shfl_xor(p1, off);
        }
        if ((t & 63) == 0) {
            int row0 = i >> 1;           // wave-uniform
            atomicAdd(&degInt[row0], p0);
            atomicAdd(&degInt[2048 + row0], p1);
        }
    }
}

// ---- fused: LDS-staged merge + masked-mean MFMA (K split x2) --------------
__launch_bounds__(512, 4)
__global__ void fused_kernel(const uint32_t* __restrict__ Mbits,
                             const uint16_t* __restrict__ aggTb,
                             const float* __restrict__ topv,
                             const int* __restrict__ topi,
                             int* __restrict__ degInt,
                             float* __restrict__ fpart) {
    int i0 = blockIdx.x * 16;
    int part = blockIdx.y;               // 0..1
    int t = threadIdx.x;
    int w = t >> 6;
    int lane = t & 63;
    int col = lane & 15;
    int quad = lane >> 4;

    __shared__ uint32_t smask[16][65];   // 64-word window + pad
    __shared__ float    lv[16][JSPLIT][TOPK];
    __shared__ uint16_t li[16][JSPLIT][TOPK];
    for (int r = t; r < 16 * 64; r += 512)
        smask[r >> 6][r & 63] =
            Mbits[(size_t)(i0 + (r >> 6)) * WPR + part * 64 + (r & 63)];
    if (t < 16 * JSPLIT) {               // 64 threads, independent loads
        int row = t & 15, q = t >> 4;
        size_t gi = (size_t)(q * N_NODES + i0 + row) * TOPK;
        #pragma unroll
        for (int k = 0; k < TOPK; ++k) {
            lv[row][q][k] = topv[gi + k];
            li[row][q][k] = (uint16_t)topi[gi + k];
        }
    }
    __syncthreads();

    if (t < 16) {                        // pure-LDS 4-way merge
        int ix[JSPLIT] = {0, 0, 0, 0};
        int newc = 0;
        int kw0 = part * 2048;
        #pragma unroll
        for (int k = 0; k < TOPK; ++k) {
            float bestv = -1e38f; int bestj = 0x7fffffff; int bestq = 0;
            #pragma unroll
            for (int q = 0; q < JSPLIT; ++q) {
                bool ok = ix[q] < TOPK;
                float fv = ok ? lv[t][q][ix[q]] : -1e38f;
                int   jj = ok ? (int)li[t][q][ix[q]] : 0x7fffffff;
                if (fv > bestv || (fv == bestv && jj < bestj)) {
                    bestv = fv; bestj = jj; bestq = q;
                }
            }
            ++ix[bestq];
            int rel = bestj - kw0;
            if (rel >= 0 && rel < 2048) {
                uint32_t* wp = &smask[t][rel >> 5];
                uint32_t old = *wp, bit = 1u << (bestj & 31);
                newc += (int)((old & bit) == 0u);
                *wp = old | bit;
            }
        }
        if (newc) atomicAdd(&degInt[i0 + t], newc);
    }
    __syncthreads();

    const uint16_t* brow = aggTb + (size_t)(w * 16 + col) * N_NODES;
    int kbase = part * 2048;
    f32x4 acc[4];
    #pragma unroll
    for (int u = 0; u < 4; ++u) acc[u] = (f32x4){0.f, 0.f, 0.f, 0.f};

    for (int k0 = 0; k0 < 2048; k0 += 128) {
        #pragma unroll
        for (int u = 0; u < 4; ++u) {
            uint32_t mw = smask[col][(k0 >> 5) + u];
            uint32_t byte = (mw >> (quad * 8)) & 0xFFu;
            union { uint32_t uu[4]; bf16x8 v; } a;
            #pragma unroll
            for (int pp = 0; pp < 4; ++pp) {
                uint32_t lo = (byte >> (2 * pp)) & 1u;
                uint32_t hi = (byte >> (2 * pp + 1)) & 1u;
                a.uu[pp] = (lo ? 0x3F80u : 0u) | (hi ? 0x3F800000u : 0u);
            }
            bf16x8 b = *(const bf16x8*)&brow[kbase + k0 + u * 32 + quad * 8];
            acc[u] = __builtin_amdgcn_mfma_f32_16x16x32_bf16(a.v, b, acc[u], 0, 0, 0);
        }
    }
    #pragma unroll
    for (int r = 0; r < 4; ++r) {
        int il = quad * 4 + r;
        float s = (acc[0][r] + acc[1][r]) + (acc[2][r] + acc[3][r]);
        fpart[(size_t)part * (N_NODES * C_DIM)
              + (size_t)(i0 + il) * C_DIM + w * 16 + col] = s;
    }
}

// ---- fused MLP: h=[x,fused]@fW+fB; h1=relu(h@l0W+l0B); out=lsm(h1@l1W+l1B)
__global__ void mlp_kernel(const float* __restrict__ xf,
                           const float* __restrict__ fpart,
                           const int* __restrict__ degInt,
                           const float* __restrict__ fW, const float* __restrict__ fB,
                           const float* __restrict__ l0W, const float* __restrict__ l0B,
                           const float* __restrict__ l1W, const float* __restrict__ l1B,
                           float* __restrict__ out) {
    int i0 = blockIdx.x * 4;
    int t = threadIdx.x;                 // 128
    __shared__ float lx[4][256];
    __shared__ float hb[4][128];
    const float* f0 = fpart;
    const float* f1 = fpart + (size_t)N_NODES * C_DIM;
    for (int r = t; r < 4 * 128; r += 128) {
        int row = r >> 7, c = r & 127;
        size_t idx = (size_t)(i0 + row) * C_DIM + c;
        lx[row][c] = xf[idx];
        lx[row][128 + c] = (f0[idx] + f1[idx])
                           / ((float)degInt[i0 + row] + 1e-6f);
    }
    __syncthreads();
    float acc[4];
    #pragma unroll
    for (int r = 0; r < 4; ++r) acc[r] = fB[t];
    for (int k = 0; k < 256; ++k) {
        float wv = fW[k * 128 + t];
        #pragma unroll
        for (int r = 0; r < 4; ++r) acc[r] = fmaf(lx[r][k], wv, acc[r]);
    }
    #pragma unroll
    for (int r = 0; r < 4; ++r) hb[r][t] = acc[r];
    __syncthreads();
    #pragma unroll
    for (int r = 0; r < 4; ++r) acc[r] = l0B[t];
    for (int k = 0; k < 128; ++k) {
        float wv = l0W[k * 128 + t];
        #pragma unroll
        for (int r = 0; r < 4; ++r) acc[r] = fmaf(hb[r][k], wv, acc[r]);
    }
    __syncthreads();
    #pragma unroll
    for (int r = 0; r < 4; ++r) lx[r][t] = fmaxf(acc[r], 0.f);   // h1
    __syncthreads();
    int o = t & 63, pr = t >> 6;
    #pragma unroll
    for (int rr = 0; rr < 2; ++rr) {
        int r = pr + 2 * rr;
        float a = l1B[o];
        for (int k = 0; k < 128; ++k)
            a = fmaf(lx[r][k], l1W[k * 64 + o], a);
        float m = a;
        #pragma unroll
        for (int off = 32; off >= 1; off >>= 1) m = fmaxf(m, __shfl_xor(m, off));
        float e = expf(a - m);
        float s = e;
        #pragma unroll
        for (int off = 32; off >= 1; off >>= 1) s += __shfl_xor(s, off);
        out[(size_t)(i0 + r) * 64 + o] = a - m - logf(s);
    }
}

extern "C" void kernel_launch(void* const* d_in, const int* in_sizes, int n_in,
                              void* d_out, int out_size, void* d_ws, size_t ws_size,
                              hipStream_t stream) {
    const float* xf    = (const float*)d_in[0];
    const int*   ei    = (const int*)d_in[1];
    const float* alpha = (const float*)d_in[2];
    const float* fW    = (const float*)d_in[3];
    const float* fB    = (const float*)d_in[4];
    const float* l0W   = (const float*)d_in[5];
    const float* l0B   = (const float*)d_in[6];
    const float* l1W   = (const float*)d_in[7];
    const float* l1B   = (const float*)d_in[8];
    float* out = (float*)d_out;
    const int E  = in_sizes[1] / 2;     // 65536
    const int NC = N_NODES * C_DIM;     // 524288

    char* p = (char*)d_ws;
    const size_t SZ = (size_t)NC * 4;   // 2 MB
    uint32_t* Abits  = (uint32_t*)p; p += SZ;
    int*      degInt = (int*)p;      p += N_NODES * 4;   // contiguous w/ Abits
    float*    hop1   = (float*)p;    p += SZ;
    uint32_t* Mbits  = (uint32_t*)p; p += SZ;
    float*    fpart  = (float*)p;    p += KSPLIT * SZ;   // two K-half partials
    uint16_t* xnb    = (uint16_t*)p; p += SZ / 2;
    uint16_t* aggTb  = (uint16_t*)p; p += SZ / 2;
    float*    topv   = (float*)p;    p += (size_t)JSPLIT * N_NODES * TOPK * 4;
    int*      topi   = (int*)p;      p += (size_t)JSPLIT * N_NODES * TOPK * 4;

    hipMemsetAsync(Abits, 0, SZ + N_NODES * 4, stream);  // Abits + degInt
    scatter_kernel<<<(E + 255) / 256, 256, 0, stream>>>(ei, E, Abits);
    spmm_norm_kernel<<<N_NODES, 128, 0, stream>>>(Abits, xf, hop1, xnb);
    combo_topk_kernel<<<2048, 512, 0, stream>>>(Abits, hop1, xf, alpha,
                                                aggTb, xnb, Mbits, degInt,
                                                topv, topi);
    fused_kernel<<<dim3(N_NODES / 16, KSPLIT), 512, 0, stream>>>(Mbits, aggTb,
                                                                 topv, topi,
                                                                 degInt, fpart);
    mlp_kernel<<<N_NODES / 4, 128, 0, stream>>>(xf, fpart, degInt,
                                                fW, fB, l0W, l0B, l1W, l1B, out);
}

// Round 21
// 226.617 us; speedup vs baseline: 1.0156x; 1.0156x over previous
//
#include <hip/hip_runtime.h>
#include <hip/hip_bf16.h>
#include <stdint.h>

// ScaleGNN on MI355X (gfx950). fp32 in / fp32 out. edge_index int32/int64
// auto-detect (in scatter). Mask = JAX threefry2x32 key(42) bit-exact.
// R21: FINAL — restore R19 (session best, 226.6 us). R20's manual prefetch
//      was neutral (compiler already hoists loads; +8 VGPR cost). Plateau
//      family R14/R15/R17/R19 = 226.6-229 us across six structural
//      experiments; remaining time is divergent insert-sort floor (~50us),
//      dispatch machinery (~55us), and small latency-bound kernels.

#define N_NODES 4096
#define C_DIM   128
#define WPR     128        // bitmask words per row (4096/32)
#define HALF_P  8388608u   // N*N/2
#define TOPK    10
#define LSTR    13         // topk list stride; (16L+13c) mod 32 covers banks
#define JSPLIT  4          // topk j-split
#define KSPLIT  2          // fused K-split

typedef __attribute__((ext_vector_type(8))) short bf16x8;   // 8 bf16 = 4 VGPRs
typedef __attribute__((ext_vector_type(4))) float f32x4;    // MFMA C/D

__device__ __forceinline__ uint16_t f2bf(float f) {         // RNE fp32->bf16
    uint32_t u = __float_as_uint(f);
    return (uint16_t)((u + 0x7FFFu + ((u >> 16) & 1u)) >> 16);
}

__device__ __forceinline__ uint32_t rotl32(uint32_t v, int r) {
    return (v << r) | (v >> (32 - r));
}

__device__ __forceinline__ void threefry2x32(uint32_t k0, uint32_t k1,
                                             uint32_t x0, uint32_t x1,
                                             uint32_t& o0, uint32_t& o1) {
    uint32_t ks2 = k0 ^ k1 ^ 0x1BD11BDAu;
    x0 += k0; x1 += k1;
#define TF_ROUND(r) { x0 += x1; x1 = rotl32(x1, (r)); x1 ^= x0; }
    TF_ROUND(13) TF_ROUND(15) TF_ROUND(26) TF_ROUND(6)
    x0 += k1;  x1 += ks2 + 1u;
    TF_ROUND(17) TF_ROUND(29) TF_ROUND(16) TF_ROUND(24)
    x0 += ks2; x1 += k0 + 2u;
    TF_ROUND(13) TF_ROUND(15) TF_ROUND(26) TF_ROUND(6)
    x0 += k0;  x1 += k1 + 3u;
    TF_ROUND(17) TF_ROUND(29) TF_ROUND(16) TF_ROUND(24)
    x0 += k1;  x1 += ks2 + 4u;
    TF_ROUND(13) TF_ROUND(15) TF_ROUND(26) TF_ROUND(6)
    x0 += ks2; x1 += k0 + 5u;
#undef TF_ROUND
    o0 = x0; o1 = x1;
}

// ---- scatter edges (int64/int32 detected per block) -----------------------
__global__ void scatter_kernel(const int* __restrict__ ei, int E,
                               uint32_t* __restrict__ Abits) {
    __shared__ int cnt_oddnz;
    int t = threadIdx.x;
    if (t == 0) cnt_oddnz = 0;
    __syncthreads();
    if (((const uint32_t*)ei)[2 * t + 1] != 0u) atomicAdd(&cnt_oddnz, 1);
    __syncthreads();
    bool is64 = (cnt_oddnz <= 8);        // int64 => high words all zero
    int e = blockIdx.x * blockDim.x + t;
    if (e >= E) return;
    int src, dst;
    if (is64) { src = ei[2 * e]; dst = ei[2 * (E + e)]; }
    else      { src = ei[e];     dst = ei[E + e]; }
    src &= (N_NODES - 1);
    dst &= (N_NODES - 1);
    atomicOr(&Abits[src * WPR + (dst >> 5)], 1u << (dst & 31));
}

// ---- SpMM + norm: hop1 = A@x; xnb = bf16(x/(||x||+1e-8)) ------------------
__global__ void spmm_norm_kernel(const uint32_t* __restrict__ Abits,
                                 const float* __restrict__ xf,
                                 float* __restrict__ hop1,
                                 uint16_t* __restrict__ xnb) {
    int i = blockIdx.x;
    int c = threadIdx.x;                 // 128
    __shared__ uint32_t wbits[WPR];
    __shared__ float ws[2];
    wbits[c] = Abits[i * WPR + c];
    __syncthreads();
    float acc = 0.f;
    for (int w = 0; w < WPR; ++w) {
        uint32_t bits = wbits[w];
        while (bits) {
            int b = __ffs(bits) - 1;
            bits &= bits - 1;
            acc += xf[(w * 32 + b) * C_DIM + c];
        }
    }
    hop1[i * C_DIM + c] = acc;
    // norm of row i
    float v = xf[i * C_DIM + c];
    float sq = v * v;
    #pragma unroll
    for (int off = 32; off >= 1; off >>= 1) sq += __shfl_xor(sq, off);
    if ((c & 63) == 0) ws[c >> 6] = sq;
    __syncthreads();
    float tot = ws[0] + ws[1];
    xnb[i * C_DIM + c] = f2bf(v / (sqrtf(tot) + 1e-8f));
}

// ---- heterogeneous: blocks 0..1023 = topk; 1024..2047 = combo -------------
__launch_bounds__(512, 4)
__global__ void combo_topk_kernel(const uint32_t* __restrict__ Abits,
                                  const float* __restrict__ hop1,
                                  const float* __restrict__ xf,
                                  const float* __restrict__ alpha,
                                  uint16_t* __restrict__ aggTb,
                                  const uint16_t* __restrict__ xnb,
                                  uint32_t* __restrict__ Mbits,
                                  int* __restrict__ degInt,
                                  float* __restrict__ topv,
                                  int* __restrict__ topi) {
    __shared__ uint8_t smem[32 * 16 * LSTR * 6];   // 39936 B overlay
    int t = threadIdx.x;

    if (blockIdx.x < 1024) {
        // ================= topk =================
        float*    sval = (float*)smem;                      // 26624 B
        uint16_t* sidx = (uint16_t*)(smem + 32 * 16 * LSTR * 4);
        int it   = blockIdx.x & 255;
        int part = blockIdx.x >> 8;      // 0..3
        int i0 = it * 16;
        int w = t >> 6;
        int lane = t & 63;
        int col = lane & 15;
        int quad = lane >> 4;

        bf16x8 bfi[4];
        #pragma unroll
        for (int s = 0; s < 4; ++s)
            bfi[s] = *(const bf16x8*)&xnb[(size_t)(i0 + col) * C_DIM + s * 32 + quad * 8];

        float tv[TOPK]; int ti[TOPK];
        #pragma unroll
        for (int k = 0; k < TOPK; ++k) { tv[k] = -1e30f; ti[k] = 0xFFFF; }

        int jt0 = part * 64 + w * 8;
        for (int p = 0; p < 8; ++p) {
            int j0 = (jt0 + p) * 16;
            f32x4 acc = {0.f, 0.f, 0.f, 0.f};
            #pragma unroll
            for (int s = 0; s < 4; ++s) {
                bf16x8 aj = *(const bf16x8*)&xnb[(size_t)(j0 + col) * C_DIM + s * 32 + quad * 8];
                acc = __builtin_amdgcn_mfma_f32_16x16x32_bf16(aj, bfi[s], acc, 0, 0, 0);
            }
            float m4 = fmaxf(fmaxf(acc[0], acc[1]), fmaxf(acc[2], acc[3]));
            if (m4 > tv[TOPK-1]) {
                #pragma unroll
                for (int r = 0; r < 4; ++r) {
                    float d = acc[r];
                    if (d > tv[TOPK-1]) {    // strict > keeps earliest j
                        int j = j0 + quad * 4 + r;
                        tv[TOPK-1] = d; ti[TOPK-1] = j;
                        #pragma unroll
                        for (int q = TOPK - 2; q >= 0; --q) {
                            if (tv[q+1] > tv[q]) {
                                float fv = tv[q]; tv[q] = tv[q+1]; tv[q+1] = fv;
                                int iv = ti[q];  ti[q] = ti[q+1];  ti[q+1] = iv;
                            }
                        }
                    }
                }
            }
        }

        int base = ((w * 4 + quad) * 16 + col) * LSTR;
        #pragma unroll
        for (int k = 0; k < TOPK; ++k) {
            sval[base + k] = tv[k];
            sidx[base + k] = (uint16_t)ti[k];
        }

        int row = t & 15, L = t >> 4;
        for (int s = 16; s >= 1; s >>= 1) {
            __syncthreads();
            if (L < s) {
                int la = (L * 16 + row) * LSTR;
                int lb = ((L + s) * 16 + row) * LSTR;
                float ov[TOPK]; uint16_t oi[TOPK];
                int ia = 0, ib = 0;
                #pragma unroll
                for (int k = 0; k < TOPK; ++k) {
                    float va = sval[la + ia], vb = sval[lb + ib];
                    uint16_t xa = sidx[la + ia], xb = sidx[lb + ib];
                    bool takeA = (va > vb) || (va == vb && xa < xb);
                    if (takeA) { ov[k] = va; oi[k] = xa; ++ia; }
                    else       { ov[k] = vb; oi[k] = xb; ++ib; }
                }
                #pragma unroll
                for (int k = 0; k < TOPK; ++k) { sval[la + k] = ov[k]; sidx[la + k] = oi[k]; }
            }
        }
        __syncthreads();
        if (t < 16) {
            size_t gi = (size_t)(part * N_NODES + i0 + t) * TOPK;
            #pragma unroll
            for (int k = 0; k < TOPK; ++k) {
                topv[gi + k] = sval[t * LSTR + k];
                topi[gi + k] = (int)sidx[t * LSTR + k];
            }
        }
    } else {
        // ================= combo (4 rows per block) =================
        uint32_t* wb = (uint32_t*)smem;  // [4][128] = 2048 B
        int bid = blockIdx.x - 1024;
        int sg = t >> 7;                 // 0..3
        int c  = t & 127;
        int i  = bid * 4 + sg;
        wb[sg * 128 + c] = Abits[i * WPR + c];
        __syncthreads();
        float acc = 0.f;
        for (int w = 0; w < WPR; ++w) {
            uint32_t bits = wb[sg * 128 + w];
            while (bits) {
                int b = __ffs(bits) - 1;
                bits &= bits - 1;
                acc += hop1[(w * 32 + b) * C_DIM + c];
            }
        }
        float xv  = xf[i * C_DIM + c];
        float h1v = hop1[i * C_DIM + c];
        float a = alpha[0] * xv + alpha[1] * h1v + alpha[2] * acc;
        aggTb[(size_t)c * N_NODES + i] = f2bf(a);   // only consumer is fused

        // threefry mask: job u = i*128 + c (bit-exact original mapping)
        uint32_t u = (uint32_t)(i * 128 + c);
        uint32_t tid = u >> 1;
        uint32_t halfb = u & 1u;
        uint32_t base = tid * 32u + halfb * 16u;
        uint32_t w0 = 0u, w1 = 0u;
        for (int k = 0; k < 16; ++k) {
            uint32_t o0, o1;
            threefry2x32(0u, 42u, base + k, HALF_P + base + k, o0, o1);
            w0 |= (uint32_t)((o0 >> 31) ^ 1u) << k;
            w1 |= (uint32_t)((o1 >> 31) ^ 1u) << k;
        }
        uint32_t w0o = (uint32_t)__shfl_xor((int)w0, 1);
        uint32_t w1o = (uint32_t)__shfl_xor((int)w1, 1);
        int p0 = 0, p1 = 0;
        if (halfb == 0u) {
            uint32_t W0 = w0 | (w0o << 16);
            uint32_t W1 = w1 | (w1o << 16);
            Mbits[tid] = W0;
            Mbits[(HALF_P >> 5) + tid] = W1;
            p0 = __popc(W0); p1 = __popc(W1);
        }
        #pragma unroll
        for (int off = 32; off >= 1; off >>= 1) {
            p0 += __shfl_xor(p0, off);
            p1 += __shfl_xor(p1, off);
        }
        if ((t & 63) == 0) {
            int row0 = i >> 1;           // wave-uniform
            atomicAdd(&degInt[row0], p0);
            atomicAdd(&degInt[2048 + row0], p1);
        }
    }
}

// ---- fused: LDS-staged merge + masked-mean MFMA (K split x2) --------------
__launch_bounds__(512, 4)
__global__ void fused_kernel(const uint32_t* __restrict__ Mbits,
                             const uint16_t* __restrict__ aggTb,
                             const float* __restrict__ topv,
                             const int* __restrict__ topi,
                             int* __restrict__ degInt,
                             float* __restrict__ fpart) {
    int i0 = blockIdx.x * 16;
    int part = blockIdx.y;               // 0..1
    int t = threadIdx.x;
    int w = t >> 6;
    int lane = t & 63;
    int col = lane & 15;
    int quad = lane >> 4;

    __shared__ uint32_t smask[16][65];   // 64-word window + pad
    __shared__ float    lv[16][JSPLIT][TOPK];
    __shared__ uint16_t li[16][JSPLIT][TOPK];
    for (int r = t; r < 16 * 64; r += 512)
        smask[r >> 6][r & 63] =
            Mbits[(size_t)(i0 + (r >> 6)) * WPR + part * 64 + (r & 63)];
    if (t < 16 * JSPLIT) {               // 64 threads, independent loads
        int row = t & 15, q = t >> 4;
        size_t gi = (size_t)(q * N_NODES + i0 + row) * TOPK;
        #pragma unroll
        for (int k = 0; k < TOPK; ++k) {
            lv[row][q][k] = topv[gi + k];
            li[row][q][k] = (uint16_t)topi[gi + k];
        }
    }
    __syncthreads();

    if (t < 16) {                        // pure-LDS 4-way merge
        int ix[JSPLIT] = {0, 0, 0, 0};
        int newc = 0;
        int kw0 = part * 2048;
        #pragma unroll
        for (int k = 0; k < TOPK; ++k) {
            float bestv = -1e38f; int bestj = 0x7fffffff; int bestq = 0;
            #pragma unroll
            for (int q = 0; q < JSPLIT; ++q) {
                bool ok = ix[q] < TOPK;
                float fv = ok ? lv[t][q][ix[q]] : -1e38f;
                int   jj = ok ? (int)li[t][q][ix[q]] : 0x7fffffff;
                if (fv > bestv || (fv == bestv && jj < bestj)) {
                    bestv = fv; bestj = jj; bestq = q;
                }
            }
            ++ix[bestq];
            int rel = bestj - kw0;
            if (rel >= 0 && rel < 2048) {
                uint32_t* wp = &smask[t][rel >> 5];
                uint32_t old = *wp, bit = 1u << (bestj & 31);
                newc += (int)((old & bit) == 0u);
                *wp = old | bit;
            }
        }
        if (newc) atomicAdd(&degInt[i0 + t], newc);
    }
    __syncthreads();

    const uint16_t* brow = aggTb + (size_t)(w * 16 + col) * N_NODES;
    int kbase = part * 2048;
    f32x4 acc[4];
    #pragma unroll
    for (int u = 0; u < 4; ++u) acc[u] = (f32x4){0.f, 0.f, 0.f, 0.f};

    for (int k0 = 0; k0 < 2048; k0 += 128) {
        #pragma unroll
        for (int u = 0; u < 4; ++u) {
            uint32_t mw = smask[col][(k0 >> 5) + u];
            uint32_t byte = (mw >> (quad * 8)) & 0xFFu;
            union { uint32_t uu[4]; bf16x8 v; } a;
            #pragma unroll
            for (int pp = 0; pp < 4; ++pp) {
                uint32_t lo = (byte >> (2 * pp)) & 1u;
                uint32_t hi = (byte >> (2 * pp + 1)) & 1u;
                a.uu[pp] = (lo ? 0x3F80u : 0u) | (hi ? 0x3F800000u : 0u);
            }
            bf16x8 b = *(const bf16x8*)&brow[kbase + k0 + u * 32 + quad * 8];
            acc[u] = __builtin_amdgcn_mfma_f32_16x16x32_bf16(a.v, b, acc[u], 0, 0, 0);
        }
    }
    #pragma unroll
    for (int r = 0; r < 4; ++r) {
        int il = quad * 4 + r;
        float s = (acc[0][r] + acc[1][r]) + (acc[2][r] + acc[3][r]);
        fpart[(size_t)part * (N_NODES * C_DIM)
              + (size_t)(i0 + il) * C_DIM + w * 16 + col] = s;
    }
}

// ---- fused MLP: h=[x,fused]@fW+fB; h1=relu(h@l0W+l0B); out=lsm(h1@l1W+l1B)
__global__ void mlp_kernel(const float* __restrict__ xf,
                           const float* __restrict__ fpart,
                           const int* __restrict__ degInt,
                           const float* __restrict__ fW, const float* __restrict__ fB,
                           const float* __restrict__ l0W, const float* __restrict__ l0B,
                           const float* __restrict__ l1W, const float* __restrict__ l1B,
                           float* __restrict__ out) {
    int i0 = blockIdx.x * 4;
    int t = threadIdx.x;                 // 128
    __shared__ float lx[4][256];
    __shared__ float hb[4][128];
    const float* f0 = fpart;
    const float* f1 = fpart + (size_t)N_NODES * C_DIM;
    for (int r = t; r < 4 * 128; r += 128) {
        int row = r >> 7, c = r & 127;
        size_t idx = (size_t)(i0 + row) * C_DIM + c;
        lx[row][c] = xf[idx];
        lx[row][128 + c] = (f0[idx] + f1[idx])
                           / ((float)degInt[i0 + row] + 1e-6f);
    }
    __syncthreads();
    float acc[4];
    #pragma unroll
    for (int r = 0; r < 4; ++r) acc[r] = fB[t];
    for (int k = 0; k < 256; ++k) {
        float wv = fW[k * 128 + t];
        #pragma unroll
        for (int r = 0; r < 4; ++r) acc[r] = fmaf(lx[r][k], wv, acc[r]);
    }
    #pragma unroll
    for (int r = 0; r < 4; ++r) hb[r][t] = acc[r];
    __syncthreads();
    #pragma unroll
    for (int r = 0; r < 4; ++r) acc[r] = l0B[t];
    for (int k = 0; k < 128; ++k) {
        float wv = l0W[k * 128 + t];
        #pragma unroll
        for (int r = 0; r < 4; ++r) acc[r] = fmaf(hb[r][k], wv, acc[r]);
    }
    __syncthreads();
    #pragma unroll
    for (int r = 0; r < 4; ++r) lx[r][t] = fmaxf(acc[r], 0.f);   // h1
    __syncthreads();
    int o = t & 63, pr = t >> 6;
    #pragma unroll
    for (int rr = 0; rr < 2; ++rr) {
        int r = pr + 2 * rr;
        float a = l1B[o];
        for (int k = 0; k < 128; ++k)
            a = fmaf(lx[r][k], l1W[k * 64 + o], a);
        float m = a;
        #pragma unroll
        for (int off = 32; off >= 1; off >>= 1) m = fmaxf(m, __shfl_xor(m, off));
        float e = expf(a - m);
        float s = e;
        #pragma unroll
        for (int off = 32; off >= 1; off >>= 1) s += __shfl_xor(s, off);
        out[(size_t)(i0 + r) * 64 + o] = a - m - logf(s);
    }
}

extern "C" void kernel_launch(void* const* d_in, const int* in_sizes, int n_in,
                              void* d_out, int out_size, void* d_ws, size_t ws_size,
                              hipStream_t stream) {
    const float* xf    = (const float*)d_in[0];
    const int*   ei    = (const int*)d_in[1];
    const float* alpha = (const float*)d_in[2];
    const float* fW    = (const float*)d_in[3];
    const float* fB    = (const float*)d_in[4];
    const float* l0W   = (const float*)d_in[5];
    const float* l0B   = (const float*)d_in[6];
    const float* l1W   = (const float*)d_in[7];
    const float* l1B   = (const float*)d_in[8];
    float* out = (float*)d_out;
    const int E  = in_sizes[1] / 2;     // 65536
    const int NC = N_NODES * C_DIM;     // 524288

    char* p = (char*)d_ws;
    const size_t SZ = (size_t)NC * 4;   // 2 MB
    uint32_t* Abits  = (uint32_t*)p; p += SZ;
    int*      degInt = (int*)p;      p += N_NODES * 4;   // contiguous w/ Abits
    float*    hop1   = (float*)p;    p += SZ;
    uint32_t* Mbits  = (uint32_t*)p; p += SZ;
    float*    fpart  = (float*)p;    p += KSPLIT * SZ;   // two K-half partials
    uint16_t* xnb    = (uint16_t*)p; p += SZ / 2;
    uint16_t* aggTb  = (uint16_t*)p; p += SZ / 2;
    float*    topv   = (float*)p;    p += (size_t)JSPLIT * N_NODES * TOPK * 4;
    int*      topi   = (int*)p;      p += (size_t)JSPLIT * N_NODES * TOPK * 4;

    hipMemsetAsync(Abits, 0, SZ + N_NODES * 4, stream);  // Abits + degInt
    scatter_kernel<<<(E + 255) / 256, 256, 0, stream>>>(ei, E, Abits);
    spmm_norm_kernel<<<N_NODES, 128, 0, stream>>>(Abits, xf, hop1, xnb);
    combo_topk_kernel<<<2048, 512, 0, stream>>>(Abits, hop1, xf, alpha,
                                                aggTb, xnb, Mbits, degInt,
                                                topv, topi);
    fused_kernel<<<dim3(N_NODES / 16, KSPLIT), 512, 0, stream>>>(Mbits, aggTb,
                                                                 topv, topi,
                                                                 degInt, fpart);
    mlp_kernel<<<N_NODES / 4, 128, 0, stream>>>(xf, fpart, degInt,
                                                fW, fB, l0W, l0B, l1W, l1B, out);
}